// Round 2
// baseline (1901.887 us; speedup 1.0000x reference)
//
#include <hip/hip_runtime.h>
#include <hip/hip_bf16.h>
#include <math.h>

// Problem dims
#define BB   4
#define TT   12
#define NN   307
#define SS   11
#define HH   64
#define NHH  4
#define EMB  152
#define NBT  48             // B*T
#define NP   320            // padded node count
#define EP   160            // padded embedding dim
#define PLP  40             // LDS P chunk pitch (shorts) in attn
#define HCP  264            // LDS hidden chunk pitch (shorts)
#define HLP  72             // LDS h1/z chunk pitch (shorts)
#define KP   72             // LDS K pitch (shorts) in scan
#define VP   328            // LDS V^T pitch (shorts) in scan
#define QOB  (4 * 320 * 64) // shorts per per-iteration Q/O buffer (128B-mult)

typedef short short8 __attribute__((ext_vector_type(8)));   // 8 bf16
typedef short short4a __attribute__((ext_vector_type(4)));  // 4 bf16
typedef float floatx4 __attribute__((ext_vector_type(4)));
#define MFMA_B16(a, b, c) __builtin_amdgcn_mfma_f32_16x16x32_bf16(a, b, c, 0, 0, 0)

__device__ __forceinline__ float wave_sum(float v) {
#pragma unroll
  for (int off = 32; off; off >>= 1) v += __shfl_xor(v, off);
  return v;
}
__device__ __forceinline__ short f2bf(float x) {
  __hip_bfloat16 h = __float2bfloat16(x);
  return *reinterpret_cast<short*>(&h);
}

// shared transpose helper (32x32 tile, fp32 -> bf16, optional scale)
__device__ __forceinline__ void xpose_tile(
    const float* __restrict__ src, __hip_bfloat16* __restrict__ dst,
    int K, int N, int bx, int by, float scale, float (*t)[33])
{
  int k0 = bx * 32, n0 = by * 32;
  int tx = threadIdx.x & 31, ty = threadIdx.x >> 5;
#pragma unroll
  for (int i = 0; i < 32; i += 8) {
    int k = k0 + ty + i, n = n0 + tx;
    if (k < K && n < N) t[ty + i][tx] = src[(long)k * N + n];
  }
  __syncthreads();
#pragma unroll
  for (int i = 0; i < 32; i += 8) {
    int n = n0 + ty + i, k = k0 + tx;
    if (k < K && n < N)
      dst[(long)n * K + k] = __float2bfloat16(t[tx][ty + i] * scale);
  }
}

// ---------------------------------------------------------------------------
// MEGA-PREP.  W_in^T only for cols 640..703 (s=10 block), Z init 1228x64
// with b_in[640+h].  Everything else as the proven R13 version.
// ---------------------------------------------------------------------------
__global__ __launch_bounds__(256) void prep_kernel(
    const float* __restrict__ ori, const float* __restrict__ W_val,
    const float* __restrict__ b_val, const float* __restrict__ tod_emb,
    const float* __restrict__ dow_emb, const float* __restrict__ node_emb,
    const float* __restrict__ W_in,
    const float* __restrict__ Wq, const float* __restrict__ Wk,
    const float* __restrict__ Wv, const float* __restrict__ Wo,
    const float* __restrict__ Wf1, const float* __restrict__ Wf2,
    const float* __restrict__ bq, const float* __restrict__ bk,
    const float* __restrict__ bv,
    const float* __restrict__ Wg1, const float* __restrict__ Wg2,
    const float* __restrict__ adj, const float* __restrict__ adj_sem,
    const float* __restrict__ b_in,
    const float* __restrict__ coeff2, const float* __restrict__ W_ce,
    const float* __restrict__ b_ce,
    __hip_bfloat16* __restrict__ xe, __hip_bfloat16* __restrict__ WinT,
    __hip_bfloat16* __restrict__ WqkvT, __hip_bfloat16* __restrict__ WoT,
    __hip_bfloat16* __restrict__ Wf1T, __hip_bfloat16* __restrict__ Wf2T,
    float* __restrict__ bqkv,
    __hip_bfloat16* __restrict__ WGPT,
    __hip_bfloat16* __restrict__ adjb, __hip_bfloat16* __restrict__ adjsb,
    float* __restrict__ Z, float* __restrict__ C2)
{
  __shared__ float t[32][33];
  int blk = blockIdx.x;

  if (blk < 9600) {                 // ---- embedding ----
    int idx = blk * 256 + threadIdx.x;
    int c = idx % EP;
    int r = idx / EP;               // bt*NP + node
    int node = r % NP;
    int bt = r / NP;
    float v = 0.f;
    if (node < NN && c < EMB) {
      long orr = (long)bt * NN + node;
      if (c < 24) {
        const float* x = ori + orr * 3;
        v = x[0] * W_val[c] + x[1] * W_val[24 + c] + x[2] * W_val[48 + c] + b_val[c];
      } else if (c < 48) {
        float f = ori[orr * 3 + 1];
        f = f - floorf(f);
        int tod = (int)(f * 288.f);
        tod = min(max(tod, 0), 287);
        v = tod_emb[tod * 24 + (c - 24)];
      } else if (c < 72) {
        float f = ori[orr * 3 + 2];
        f = f - floorf(f);
        int dow = (int)(f * 7.f);
        dow = min(max(dow, 0), 6);
        v = dow_emb[dow * 24 + (c - 48)];
      } else {
        v = node_emb[node * 80 + (c - 72)];
      }
    }
    xe[idx] = __float2bfloat16(v);
  } else if (blk < 9714) {          // ---- W_in transpose, s=10 cols only ----
    int q = blk - 9600;             // 57 x 2 tiles (cols 640..703)
    xpose_tile(W_in, WinT, 1824, 704, q % 57, 20 + q / 57, 1.f, t);
  } else if (blk < 9763) {          // ---- small-weight transposes + bias ----
    int b2 = blk - 9714;
    if (b2 == 48) {
      int th = threadIdx.x;
      if (th < 64) {
        bqkv[th] = bq[th] * 0.25f;  // score scale folded into q
        bqkv[64 + th] = bk[th];
        bqkv[128 + th] = bv[th];
      }
      return;
    }
    const float* src; __hip_bfloat16* dst;
    int K, N, bx, by; float scale = 1.f;
    if (b2 < 4)       { src = Wq;  dst = WqkvT;           K = 64;  N = 64;  bx = b2 & 1;        by = b2 >> 1;        scale = 0.25f; }
    else if (b2 < 8)  { src = Wk;  dst = WqkvT + 64 * 64; K = 64;  N = 64;  bx = (b2 - 4) & 1;  by = (b2 - 4) >> 1; }
    else if (b2 < 12) { src = Wv;  dst = WqkvT + 128 * 64;K = 64;  N = 64;  bx = (b2 - 8) & 1;  by = (b2 - 8) >> 1; }
    else if (b2 < 16) { src = Wo;  dst = WoT;             K = 64;  N = 64;  bx = (b2 - 12) & 1; by = (b2 - 12) >> 1; }
    else if (b2 < 32) { src = Wf1; dst = Wf1T;            K = 64;  N = 256; bx = (b2 - 16) % 2; by = (b2 - 16) / 2; }
    else              { src = Wf2; dst = Wf2T;            K = 256; N = 64;  bx = (b2 - 32) % 8; by = (b2 - 32) / 8; }
    xpose_tile(src, dst, K, N, bx, by, scale, t);
  } else {                          // ---- packs + Z init + C2 ----
    int b3 = blk - 9763;
    if (b3 < 80) {
      int idx = b3 * 256 + threadIdx.x;           // < 128*160
      int c = idx / EP, k = idx % EP;
      float v = 0.f;
      if (k < EMB) v = (c < 64) ? Wg1[k * 64 + c] : Wg2[k * 64 + (c - 64)];
      WGPT[idx] = __float2bfloat16(v);
    } else if (b3 < 480) {
      int idx = (b3 - 80) * 256 + threadIdx.x;    // < 320*320
      int m = idx / NP, k = idx % NP;
      float v1 = 0.f, v2 = 0.f;
      if (m < NN && k < NN) { v1 = adj[m * NN + k]; v2 = adj_sem[m * NN + k]; }
      adjb[idx] = __float2bfloat16(v1);
      adjsb[idx] = __float2bfloat16(v2);
    } else if (b3 < 787) {
      int idx = (b3 - 480) * 256 + threadIdx.x;   // < 1228*64
      Z[idx] = b_in[640 + (idx & 63)];
    } else {
      int idx = (b3 - 787) * 256 + threadIdx.x;   // < 13508*64
      int row = idx >> 6, h = idx & 63;           // row = (b*N+n)*S + s
      float a0 = coeff2[(long)row * 2];
      float a1 = coeff2[(long)row * 2 + 1];
      C2[idx] = a0 * W_ce[h] + a1 * W_ce[64 + h] + b_ce[h];
    }
  }
}

// ---------------------------------------------------------------------------
// xg_mfma (unchanged)
// ---------------------------------------------------------------------------
__global__ __launch_bounds__(256) void xg_mfma(
    const __hip_bfloat16* __restrict__ XE, const __hip_bfloat16* __restrict__ WGPT,
    __hip_bfloat16* __restrict__ XGT)
{
  int bt = blockIdx.x;
  int tid = threadIdx.x, w = tid >> 6, l = tid & 63;
  int m0 = blockIdx.y * 64 + w * 16;      // node tile
  int cq = l & 15, rq = l >> 4;

  short8 af[5];
  const short* Ap = (const short*)XE + ((long)bt * NP + m0 + cq) * EP + rq * 8;
#pragma unroll
  for (int kk = 0; kk < 5; ++kk) af[kk] = *(const short8*)(Ap + kk * 32);

#pragma unroll
  for (int ct = 0; ct < 8; ++ct) {
    const short* Bp = (const short*)WGPT + (long)(ct * 16 + cq) * EP + rq * 8;
    floatx4 acc = {0.f, 0.f, 0.f, 0.f};
#pragma unroll
    for (int kk = 0; kk < 5; ++kk)
      acc = MFMA_B16(af[kk], *(const short8*)(Bp + kk * 32), acc);
    short4a pk;
#pragma unroll
    for (int r = 0; r < 4; ++r) pk[r] = f2bf(acc[r]);
    *(short4a*)((short*)XGT + ((long)bt * 128 + ct * 16 + cq) * NP + m0 + rq * 4) = pk;
  }
}

// ---------------------------------------------------------------------------
// gcn_mfma (unchanged)
// ---------------------------------------------------------------------------
__global__ __launch_bounds__(256) void gcn_mfma(
    const __hip_bfloat16* __restrict__ XGT, const __hip_bfloat16* __restrict__ adjb,
    const __hip_bfloat16* __restrict__ adjsb, const float* __restrict__ bg,
    float* __restrict__ GT)
{
  int bt = blockIdx.x;
  int tid = threadIdx.x, w = tid >> 6, l = tid & 63;
  int n0 = blockIdx.y * 64;
  int cq = l & 15, rq = l >> 4;

  short8 a1[10], a2[10];
  const short* A1p = (const short*)XGT + ((long)bt * 128 + w * 16 + cq) * NP + rq * 8;
  const short* A2p = A1p + 64 * NP;
#pragma unroll
  for (int kk = 0; kk < 10; ++kk) {
    a1[kk] = *(const short8*)(A1p + kk * 32);
    a2[kk] = *(const short8*)(A2p + kk * 32);
  }

  float bgv[4];
#pragma unroll
  for (int r = 0; r < 4; ++r) bgv[r] = bg[w * 16 + rq * 4 + r];

#pragma unroll
  for (int nt = 0; nt < 4; ++nt) {
    const short* B1p = (const short*)adjb + (long)(n0 + nt * 16 + cq) * NP + rq * 8;
    const short* B2p = (const short*)adjsb + (long)(n0 + nt * 16 + cq) * NP + rq * 8;
    floatx4 acc = {0.f, 0.f, 0.f, 0.f};
#pragma unroll
    for (int kk = 0; kk < 10; ++kk) {
      acc = MFMA_B16(a1[kk], *(const short8*)(B1p + kk * 32), acc);
      acc = MFMA_B16(a2[kk], *(const short8*)(B2p + kk * 32), acc);
    }
    int node = n0 + nt * 16 + cq;
    if (node < NN) {
      float4 pk;
      pk.x = fmaxf(acc[0] + bgv[0], 0.f);
      pk.y = fmaxf(acc[1] + bgv[1], 0.f);
      pk.z = fmaxf(acc[2] + bgv[2], 0.f);
      pk.w = fmaxf(acc[3] + bgv[3], 0.f);
      *(float4*)(GT + (((long)bt * NP + node) * 64 + w * 16 + rq * 4)) = pk;
    }
  }
}

// ---------------------------------------------------------------------------
// x_in GEMM — s=10 output block only (N: 704 -> 64).  grid (20, 4).
// ---------------------------------------------------------------------------
__global__ __launch_bounds__(256) void gemm_xin(
    const __hip_bfloat16* __restrict__ XE, const __hip_bfloat16* __restrict__ BT,
    float* __restrict__ C)
{
  int tid = threadIdx.x, w = tid >> 6, l = tid & 63;
  int m0 = blockIdx.x * 64 + w * 16;
  const int n0 = 640;                 // s=10 column block of W_in
  int k0s = blockIdx.y * 480;
  int k0e = min(1824, k0s + 480);

  int cq = l & 15, rq = l >> 4;
  int arow = min(m0 + cq, 1227);
  int ab = arow / NN, an = arow - ab * NN;
  const short* Abase = (const short*)XE;
  const short* Bp = (const short*)BT + rq * 8;

  floatx4 acc[4] = {};
  for (int k0 = k0s; k0 < k0e; k0 += 32) {
    int kk = k0 + rq * 8;
    int t = kk / EMB;
    int c = kk - t * EMB;
    short8 a = *(const short8*)(Abase + (((long)(ab * TT + t)) * NP + an) * EP + c);
#pragma unroll
    for (int nt = 0; nt < 4; ++nt) {
      short8 b = *(const short8*)(Bp + (long)(n0 + nt * 16 + cq) * 1824 + k0);
      acc[nt] = MFMA_B16(a, b, acc[nt]);
    }
  }
#pragma unroll
  for (int nt = 0; nt < 4; ++nt) {
    int c = nt * 16 + cq;
#pragma unroll
    for (int r = 0; r < 4; ++r) {
      int row = m0 + rq * 4 + r;
      if (row < 1228) atomicAdd(&C[(long)row * 64 + c], acc[nt][r]);
    }
  }
}

// ---------------------------------------------------------------------------
// HeteroGCN head (gp half of old gp_qkv; QKV moved into euler_scan)
// ---------------------------------------------------------------------------
__global__ __launch_bounds__(256) void gcn_out(
    const float* __restrict__ GT, const float* __restrict__ Wgo,
    const float* __restrict__ bgo, const float* __restrict__ w_het,
    float* __restrict__ out)
{
  __shared__ float buf[4][TT * 64];
  int wave = threadIdx.x >> 6, lane = threadIdx.x & 63;
  int bn = blockIdx.x * 4 + wave;        // 307*4 = 1228 exact
  int b = bn / NN, n = bn % NN;
  float* bw = buf[wave];
  for (int idx = lane; idx < TT * 64; idx += 64) {
    int t = idx >> 6, h = idx & 63;
    bw[idx] = GT[(((long)(b * TT + t)) * NP + n) * 64 + h];
  }
  float acc[12] = {};
#pragma unroll
  for (int j = 0; j < 12; ++j) {
    int k = j * 64 + lane;
    float g = bw[k];
    const float* wr = Wgo + (long)k * 12;
#pragma unroll
    for (int o = 0; o < 12; ++o) acc[o] += g * wr[o];
  }
#pragma unroll
  for (int o = 0; o < 12; ++o) acc[o] = wave_sum(acc[o]);
  if (lane == 0) {
    float wh = w_het[0];
#pragma unroll
    for (int o = 0; o < 12; ++o)
      out[((long)b * 12 + o) * NN + n] = wh * (acc[o] + bgo[o]);
  }
}

// ---------------------------------------------------------------------------
// LN stats helper: two-pass mean/var over 64 cols split as 16 lanes x 4 waves.
// Two Red banks -> 2 block barriers per LN (WAR-safe).
// ---------------------------------------------------------------------------
__device__ __forceinline__ void ln_stats4(
    const float* x, float (*R0)[16], float (*R1)[16],
    int w, int cq, int rq, float* mean, float* rstd)
{
  float p[4];
#pragma unroll
  for (int r = 0; r < 4; ++r) {
    float s = x[r];
#pragma unroll
    for (int o2 = 1; o2 <= 8; o2 <<= 1) s += __shfl_xor(s, o2);
    p[r] = s;
  }
  if (cq == 0) {
#pragma unroll
    for (int r = 0; r < 4; ++r) R0[w][rq * 4 + r] = p[r];
  }
  __syncthreads();
#pragma unroll
  for (int r = 0; r < 4; ++r) {
    int rr = rq * 4 + r;
    mean[r] = (R0[0][rr] + R0[1][rr] + R0[2][rr] + R0[3][rr]) * (1.f / 64.f);
  }
#pragma unroll
  for (int r = 0; r < 4; ++r) {
    float d = x[r] - mean[r];
    float s = d * d;
#pragma unroll
    for (int o2 = 1; o2 <= 8; o2 <<= 1) s += __shfl_xor(s, o2);
    p[r] = s;
  }
  if (cq == 0) {
#pragma unroll
    for (int r = 0; r < 4; ++r) R1[w][rq * 4 + r] = p[r];
  }
  __syncthreads();
#pragma unroll
  for (int r = 0; r < 4; ++r) {
    int rr = rq * 4 + r;
    float vs = R1[0][rr] + R1[1][rr] + R1[2][rr] + R1[3][rr];
    rstd[r] = rsqrtf(vs * (1.f / 64.f) + 1e-5f);
  }
}

// ---------------------------------------------------------------------------
// euler_scan: one persistent 1024-thread block per batch b.  Only the s=10
// slice is live (the reference consumes zf[:,:,-1,:] only; slices are
// independent).  K/V^T live in LDS across all 11 iterations; Q and O go
// through per-iteration 128B-aligned global buffers (fresh lines each
// iteration -> no stale-L1 hazard on the intra-kernel global RAW).
//   attn phase : 80 (head,qgroup) tasks over 16 waves (proven attn_mfma body)
//   step phase : 4 teams x 4 waves, 5 row-tiles each (proven block_step3 body)
// ---------------------------------------------------------------------------
__global__ __launch_bounds__(1024) void euler_scan(
    float* __restrict__ Z, const float* __restrict__ C2,
    const float* __restrict__ W_tp2, const float* __restrict__ b_tp2,
    const __hip_bfloat16* __restrict__ WqkvT, const float* __restrict__ bqkv,
    const __hip_bfloat16* __restrict__ WoT, const float* __restrict__ bo,
    const float* __restrict__ ln1g, const float* __restrict__ ln1b,
    const __hip_bfloat16* __restrict__ Wf1T, const float* __restrict__ bf1,
    const __hip_bfloat16* __restrict__ Wf2T, const float* __restrict__ bf2,
    const float* __restrict__ ln2g, const float* __restrict__ ln2b,
    const float* __restrict__ lnfg, const float* __restrict__ lnfb,
    const float* __restrict__ W_end, const float* __restrict__ b_end,
    const float* __restrict__ w_acl, float* __restrict__ out,
    short* __restrict__ Qbufs, short* __restrict__ Obufs)
{
  __shared__ __align__(16) short KL[320 * KP];   // 46080 B
  __shared__ __align__(16) short VT[64 * VP];    // 41984 B
  __shared__ __align__(16) short UN[21504];      // 43008 B: Pd (attn) / Hl+Hc (step)
  __shared__ float Red[2][4][4][16];             // 2048 B

  const short8 z8 = {0, 0, 0, 0, 0, 0, 0, 0};
  const floatx4 zf4 = {0.f, 0.f, 0.f, 0.f};

  int b = blockIdx.x;
  int tid = threadIdx.x;
  int w16 = tid >> 6, l = tid & 63;
  int cq = l & 15, rq = l >> 4;
  int team = w16 >> 2, w = w16 & 3;

  // V^T cols >= NN must stay zero forever (PV reads them unmasked)
  for (int i = tid; i < 64 * VP; i += 1024) VT[i] = 0;
  __syncthreads();

  // ---- initial QKV from Z (fp32) ----
#pragma unroll 1
  for (int tile = w16; tile < 20; tile += 16) {
    int node0 = tile * 16 + cq;
    int nc = min(node0, NN - 1);
    const float* zp = Z + (nc + b * NN) * 64 + rq * 8;
    short8 za0, za1;
#pragma unroll
    for (int j = 0; j < 8; ++j) { za0[j] = f2bf(zp[j]); za1[j] = f2bf(zp[32 + j]); }
#pragma unroll 1
    for (int nt = 0; nt < 12; ++nt) {
      const short* Bq = (const short*)WqkvT + (nt * 16 + cq) * 64 + rq * 8;
      floatx4 ac = zf4;
      ac = MFMA_B16(za0, *(const short8*)Bq, ac);
      ac = MFMA_B16(za1, *(const short8*)(Bq + 32), ac);
      int c = nt * 16 + cq;
      float bias = bqkv[c];
#pragma unroll
      for (int r = 0; r < 4; ++r) {
        int nd = tile * 16 + rq * 4 + r;
        if (nd < NN) {
          short v = f2bf(ac[r] + bias);
          if (c < 64)       Qbufs[(b * 320 + nd) * 64 + c] = v;
          else if (c < 128) KL[nd * KP + (c - 64)] = v;
          else              VT[(c - 128) * VP + nd] = v;
        }
      }
    }
  }
  __syncthreads();

  // iter-invariant per-lane constants (step phase)
  int col = w * 16 + cq;
  float g1 = ln1g[col], b1 = ln1b[col];
  float g2 = ln2g[col], b2v = ln2b[col];
  float f2 = bf2[col];
  float bov = bo[col];
  const short* Bwo = (const short*)WoT + col * 64 + rq * 8;
  const short* Bf2 = (const short*)Wf2T + col * 256 + rq * 8;
  short* Hlt = &UN[team * 5376];
  short* Hct = Hlt + 16 * HLP;

#pragma unroll 1
  for (int iter = 0; iter < SS; ++iter) {
    const short* Qc = Qbufs + iter * QOB;
    short* Oc = Obufs + iter * QOB;

    // ================= attention phase =================
    {
      int m = cq, quad = rq;
      short* Pw0 = &UN[w16 * 1280];
      short* Pw1 = Pw0 + 640;
#pragma unroll 1
      for (int t5 = 0; t5 < 5; ++t5) {
        int task = w16 + (t5 << 4);      // 0..79
        int head = task & 3, g = task >> 2;
        int qv = g * 16 + m;
        short8 qf = z8;
        if (quad < 2 && qv < NN)
          qf = *(const short8*)(Qc + (b * 320 + qv) * 64 + head * 16 + quad * 8);
        float sum = 0.f;
        floatx4 oa = zf4, ob = zf4;
        const short* Vb = &VT[(head * 16 + m) * VP];
        for (int c = 0; c < 10; ++c) {
          short8 kf0 = z8, kf1 = z8;
          if (quad < 2) {
            kf0 = *(const short8*)&KL[((2 * c) * 16 + m) * KP + head * 16 + quad * 8];
            kf1 = *(const short8*)&KL[((2 * c + 1) * 16 + m) * KP + head * 16 + quad * 8];
          }
          floatx4 s0 = MFMA_B16(kf0, qf, zf4);
          floatx4 s1 = MFMA_B16(kf1, qf, zf4);
          float e0[4], e1[4];
#pragma unroll
          for (int j = 0; j < 4; ++j) {
            e0[j] = __expf(fminf(s0[j], 30.f));
            e1[j] = __expf(fminf(s1[j], 30.f));
          }
          if (c == 9) {                  // keys >= 307 masked out
            if (quad == 0) e1[3] = 0.f;
            else { e1[0] = 0.f; e1[1] = 0.f; e1[2] = 0.f; e1[3] = 0.f; }
          }
          sum += e0[0] + e0[1] + e0[2] + e0[3] + e1[0] + e1[1] + e1[2] + e1[3];
          short4a p0, p1;
#pragma unroll
          for (int j = 0; j < 4; ++j) { p0[j] = f2bf(e0[j]); p1[j] = f2bf(e1[j]); }
          short* Pw = (c & 1) ? Pw1 : Pw0;
          *(short4a*)&Pw[m * PLP + quad * 4] = p0;
          *(short4a*)&Pw[m * PLP + 16 + quad * 4] = p1;
          short8 pf = *(const short8*)&Pw[m * PLP + quad * 8];
          short8 vf = *(const short8*)(Vb + c * 32 + quad * 8);
          if (c & 1) ob = MFMA_B16(vf, pf, ob);
          else       oa = MFMA_B16(vf, pf, oa);
        }
        sum += __shfl_xor(sum, 16);
        sum += __shfl_xor(sum, 32);
        float inv = 1.f / sum;
        if (qv < NN) {
          short4a pk;
#pragma unroll
          for (int r = 0; r < 4; ++r) pk[r] = f2bf((oa[r] + ob[r]) * inv);
          *(short4a*)(Oc + (b * 320 + qv) * 64 + head * 16 + quad * 4) = pk;
        }
      }
    }
    __syncthreads();   // O complete; Pd free; KL/VT writable

    // ================= step phase (4 teams x 5 tiles) =================
    float wt[SS];
#pragma unroll
    for (int s2 = 0; s2 < SS; ++s2) wt[s2] = W_tp2[s2 * (SS * SS) + 110 + iter];
    float btp = b_tp2[110 + iter];

#pragma unroll 1
    for (int j5 = 0; j5 < 5; ++j5) {
      int tile = team + (j5 << 2);
      int m0 = tile * 16;

      // ---- Wo GEMM + residual (A-row clamped: rows >= NN are masked) ----
      int arow = min(m0 + cq, NN - 1);
      const short* Ap = Oc + (b * 320 + arow) * 64 + rq * 8;
      short8 a0 = *(const short8*)Ap;
      short8 a1 = *(const short8*)(Ap + 32);
      floatx4 acc0 = zf4;
      acc0 = MFMA_B16(a0, *(const short8*)Bwo, acc0);
      acc0 = MFMA_B16(a1, *(const short8*)(Bwo + 32), acc0);
      float x[4];
      bool val[4]; int zov[4], bnv[4];
#pragma unroll
      for (int r = 0; r < 4; ++r) {
        int nodev = m0 + rq * 4 + r;
        val[r] = nodev < NN;
        int nc = min(nodev, NN - 1);
        bnv[r] = b * NN + nc;
        zov[r] = bnv[r] * 64;
        x[r] = acc0[r] + bov + Z[zov[r] + col];
      }
      // ---- LN1 ----
      float mean[4], rstd[4];
      ln_stats4(x, Red[0][team], Red[1][team], w, cq, rq, mean, rstd);
      float h1r[4];
#pragma unroll
      for (int r = 0; r < 4; ++r) {
        float h = (x[r] - mean[r]) * rstd[r] * g1 + b1;
        h1r[r] = h;
        Hlt[(rq * 4 + r) * HLP + col] = f2bf(h);
      }
      __syncthreads();   // h1 chunk complete
      // ---- FFN A ----
      short8 ha0 = *(const short8*)&Hlt[cq * HLP + rq * 8];
      short8 ha1 = *(const short8*)&Hlt[cq * HLP + 32 + rq * 8];
#pragma unroll
      for (int jj = 0; jj < 4; ++jj) {
        int ht = w * 4 + jj;
        const short* Bq = (const short*)Wf1T + (ht * 16 + cq) * 64 + rq * 8;
        floatx4 ac = zf4;
        ac = MFMA_B16(ha0, *(const short8*)Bq, ac);
        ac = MFMA_B16(ha1, *(const short8*)(Bq + 32), ac);
        float bv = bf1[ht * 16 + cq];
#pragma unroll
        for (int r = 0; r < 4; ++r)
          Hct[(rq * 4 + r) * HCP + ht * 16 + cq] = f2bf(fmaxf(ac[r] + bv, 0.f));
      }
      __syncthreads();   // hidden chunk complete
      // ---- FFN B ----
      {
        floatx4 ac = zf4;
#pragma unroll
        for (int kk = 0; kk < 8; ++kk) {
          short8 pf = *(const short8*)&Hct[cq * HCP + kk * 32 + rq * 8];
          ac = MFMA_B16(pf, *(const short8*)(Bf2 + kk * 32), ac);
        }
#pragma unroll
        for (int r = 0; r < 4; ++r) x[r] = h1r[r] + ac[r] + f2;
      }
      __syncthreads();   // Hc reads done (Fin may reuse)
      // ---- LN2 ----
      ln_stats4(x, Red[0][team], Red[1][team], w, cq, rq, mean, rstd);
      // ---- tanh + Euler update ----
#pragma unroll
      for (int r = 0; r < 4; ++r) {
        float t = tanhf((x[r] - mean[r]) * rstd[r] * g2 + b2v);
        float accw = btp;
#pragma unroll
        for (int s2 = 0; s2 < SS; ++s2)
          accw += C2[(bnv[r] * SS + s2) * 64 + col] * wt[s2];
        if (val[r]) {
          float zn = Z[zov[r] + col] + t * accw;
          Z[zov[r] + col] = zn;
          Hlt[(rq * 4 + r) * HLP + col] = f2bf(zn);
          x[r] = zn;
        }
      }
      __syncthreads();   // zn chunk complete

      if (iter < SS - 1) {
        // ---- QKV for next iter: Q -> global buf iter+1, K/V -> LDS ----
        short8 zb0 = *(const short8*)&Hlt[cq * HLP + rq * 8];
        short8 zb1 = *(const short8*)&Hlt[cq * HLP + 32 + rq * 8];
        short* Qn = Qbufs + (iter + 1) * QOB;
#pragma unroll
        for (int jj = 0; jj < 3; ++jj) {
          int nt = w * 3 + jj;
          const short* Bq = (const short*)WqkvT + (nt * 16 + cq) * 64 + rq * 8;
          floatx4 ac = zf4;
          ac = MFMA_B16(zb0, *(const short8*)Bq, ac);
          ac = MFMA_B16(zb1, *(const short8*)(Bq + 32), ac);
          int c = nt * 16 + cq;
          float bias = bqkv[c];
#pragma unroll
          for (int r = 0; r < 4; ++r) {
            int nd = m0 + rq * 4 + r;
            if (nd < NN) {
              short v = f2bf(ac[r] + bias);
              if (c < 64)       Qn[(b * 320 + nd) * 64 + c] = v;
              else if (c < 128) KL[nd * KP + (c - 64)] = v;
              else              VT[(c - 128) * VP + nd] = v;
            }
          }
        }
      } else {
        // ---- final: zT = LN(zn; lnf); out += w_acl*(zT@W_end + b_end) ----
        ln_stats4(x, Red[0][team], Red[1][team], w, cq, rq, mean, rstd);
        float gf = lnfg[col], bff = lnfb[col];
        float zT[4];
#pragma unroll
        for (int r = 0; r < 4; ++r)
          zT[r] = (x[r] - mean[r]) * rstd[r] * gf + bff;
        float* Fin = (float*)Hct;   // Hc free after FFN-B barrier
#pragma unroll
        for (int o = 0; o < 12; ++o) {
          float pr[4];
#pragma unroll
          for (int r = 0; r < 4; ++r) {
            float p = zT[r] * W_end[col * 12 + o];
#pragma unroll
            for (int o2 = 1; o2 <= 8; o2 <<= 1) p += __shfl_xor(p, o2);
            pr[r] = p;
          }
          if (cq == 0) {
#pragma unroll
            for (int r = 0; r < 4; ++r) Fin[(o * 4 + w) * 16 + rq * 4 + r] = pr[r];
          }
        }
        __syncthreads();
        if (w == 0 && l < 16) {
          int nd = m0 + l;
          if (nd < NN) {
            float wa = w_acl[0];
#pragma unroll
            for (int o = 0; o < 12; ++o) {
              float p = Fin[(o * 4 + 0) * 16 + l] + Fin[(o * 4 + 1) * 16 + l] +
                        Fin[(o * 4 + 2) * 16 + l] + Fin[(o * 4 + 3) * 16 + l];
              int oi = (b * 12 + o) * NN + nd;
              out[oi] = out[oi] + wa * (p + b_end[o]);
            }
          }
        }
      }
    }  // tile loop
    __syncthreads();   // KL/VT complete for next iteration
  }  // iter loop
}

// ---------------------------------------------------------------------------
extern "C" void kernel_launch(void* const* d_in, const int* in_sizes, int n_in,
                              void* d_out, int out_size, void* d_ws, size_t ws_size,
                              hipStream_t stream)
{
  (void)in_sizes; (void)n_in; (void)out_size; (void)ws_size;

  const float* ori_x    = (const float*)d_in[0];
  const float* coeff2   = (const float*)d_in[2];
  const float* W_val    = (const float*)d_in[5];
  const float* b_val    = (const float*)d_in[6];
  const float* tod_emb  = (const float*)d_in[7];
  const float* dow_emb  = (const float*)d_in[8];
  const float* node_emb = (const float*)d_in[9];
  const float* W_in     = (const float*)d_in[10];
  const float* b_in     = (const float*)d_in[11];
  const float* W_ce     = (const float*)d_in[12];
  const float* b_ce     = (const float*)d_in[13];
  const float* W_tp2    = (const float*)d_in[14];
  const float* b_tp2    = (const float*)d_in[15];
  const float* Wq = (const float*)d_in[20];
  const float* Wk = (const float*)d_in[21];
  const float* Wv = (const float*)d_in[22];
  const float* Wo = (const float*)d_in[23];
  const float* bq = (const float*)d_in[24];
  const float* bk = (const float*)d_in[25];
  const float* bv = (const float*)d_in[26];
  const float* bo = (const float*)d_in[27];
  const float* ln1_g = (const float*)d_in[28];
  const float* ln1_b = (const float*)d_in[29];
  const float* Wf1   = (const float*)d_in[30];
  const float* bf1   = (const float*)d_in[31];
  const float* Wf2   = (const float*)d_in[32];
  const float* bf2   = (const float*)d_in[33];
  const float* ln2_g = (const float*)d_in[34];
  const float* ln2_b = (const float*)d_in[35];
  const float* lnf_g = (const float*)d_in[36];
  const float* lnf_b = (const float*)d_in[37];
  const float* W_end = (const float*)d_in[38];
  const float* b_end = (const float*)d_in[39];
  const float* w_acl = (const float*)d_in[40];
  const float* w_het = (const float*)d_in[41];
  const float* adj     = (const float*)d_in[42];
  const float* adj_sem = (const float*)d_in[43];
  const float* Wg1 = (const float*)d_in[44];
  const float* Wg2 = (const float*)d_in[45];
  const float* bg  = (const float*)d_in[46];
  const float* Wgo = (const float*)d_in[47];
  const float* bgo = (const float*)d_in[48];
  float* out = (float*)d_out;
  float* ws  = (float*)d_ws;

  // ---- workspace layout (float offsets; Q/O buffers 128B-aligned) ----
  float* Z  = ws;                                            // 1228*64 = 78592
  float* C2 = ws + 78592;                                    // 13508*64 = 864512
  __hip_bfloat16* WinT  = (__hip_bfloat16*)(ws + 943104);    // 704*1824 bf16 (rows 640..703 filled)
  __hip_bfloat16* WqkvT = (__hip_bfloat16*)(ws + 1585152);   // 192*64
  __hip_bfloat16* WoT   = (__hip_bfloat16*)(ws + 1591296);   // 64*64
  __hip_bfloat16* Wf1T  = (__hip_bfloat16*)(ws + 1593344);   // 256*64
  __hip_bfloat16* Wf2T  = (__hip_bfloat16*)(ws + 1601536);   // 64*256
  float* BQKV = ws + 1609728;                                // 192 (+pad to 256)
  short* Qbufs = (short*)(ws + 1609984);                     // 12 x QOB bf16 (128B-aligned)
  short* Obufs = (short*)(ws + 2101504);                     // 11 x QOB bf16 (128B-aligned)
  float* POOL = ws + 2552064;
  __hip_bfloat16* XEMBb = (__hip_bfloat16*)POOL;             // 48*320*160
  __hip_bfloat16* XGT   = (__hip_bfloat16*)(POOL + 1228800); // 48*128*320
  float* GT             = POOL + 2211840;                    // 48*320*64 fp32
  __hip_bfloat16* ADJB  = (__hip_bfloat16*)(POOL + 3194880); // 320*320
  __hip_bfloat16* ADJSB = (__hip_bfloat16*)(POOL + 3246080); // 320*320
  __hip_bfloat16* WGPT  = (__hip_bfloat16*)(POOL + 3297280); // 128*160

  // ---- phase 1 ----
  prep_kernel<<<dim3(13927), dim3(256), 0, stream>>>(
      ori_x, W_val, b_val, tod_emb, dow_emb, node_emb, W_in,
      Wq, Wk, Wv, Wo, Wf1, Wf2, bq, bk, bv,
      Wg1, Wg2, adj, adj_sem, b_in, coeff2, W_ce, b_ce,
      XEMBb, WinT, WqkvT, WoT, Wf1T, Wf2T, BQKV,
      WGPT, ADJB, ADJSB, Z, C2);
  gemm_xin<<<dim3(20, 4), dim3(256), 0, stream>>>(XEMBb, WinT, Z);
  xg_mfma<<<dim3(NBT, 5), dim3(256), 0, stream>>>(XEMBb, WGPT, XGT);
  gcn_mfma<<<dim3(NBT, 5), dim3(256), 0, stream>>>(XGT, ADJB, ADJSB, bg, GT);
  gcn_out<<<dim3(307), dim3(256), 0, stream>>>(GT, Wgo, bgo, w_het, out);

  // ---- phase 2: whole Euler scan, one persistent block per batch ----
  euler_scan<<<dim3(BB), dim3(1024), 0, stream>>>(
      Z, C2, W_tp2, b_tp2, WqkvT, BQKV, WoT, bo, ln1_g, ln1_b,
      Wf1T, bf1, Wf2T, bf2, ln2_g, ln2_b, lnf_g, lnf_b,
      W_end, b_end, w_acl, out, Qbufs, Obufs);
}

// Round 3
// 473.888 us; speedup vs baseline: 4.0134x; 4.0134x over previous
//
#include <hip/hip_runtime.h>
#include <hip/hip_bf16.h>
#include <math.h>

// Problem dims
#define BB   4
#define TT   12
#define NN   307
#define SS   11
#define HH   64
#define NHH  4
#define EMB  152
#define NBT  48             // B*T
#define NP   320            // padded node count
#define EP   160            // padded embedding dim
#define PLP  40             // LDS P chunk pitch (shorts) in attn
#define HCP  264            // LDS hidden chunk pitch (shorts)
#define HLP  72             // LDS h1/z chunk pitch (shorts)
#define KP   72             // LDS K pitch (shorts)
#define VP   328            // LDS V^T pitch (shorts)
#define OTP  72             // LDS O tile pitch (shorts)

typedef short short8 __attribute__((ext_vector_type(8)));   // 8 bf16
typedef short short4a __attribute__((ext_vector_type(4)));  // 4 bf16
typedef float floatx4 __attribute__((ext_vector_type(4)));
#define MFMA_B16(a, b, c) __builtin_amdgcn_mfma_f32_16x16x32_bf16(a, b, c, 0, 0, 0)

__device__ __forceinline__ float wave_sum(float v) {
#pragma unroll
  for (int off = 32; off; off >>= 1) v += __shfl_xor(v, off);
  return v;
}
__device__ __forceinline__ short f2bf(float x) {
  __hip_bfloat16 h = __float2bfloat16(x);
  return *reinterpret_cast<short*>(&h);
}

// shared transpose helper (32x32 tile, fp32 -> bf16, optional scale)
__device__ __forceinline__ void xpose_tile(
    const float* __restrict__ src, __hip_bfloat16* __restrict__ dst,
    int K, int N, int bx, int by, float scale, float (*t)[33])
{
  int k0 = bx * 32, n0 = by * 32;
  int tx = threadIdx.x & 31, ty = threadIdx.x >> 5;
#pragma unroll
  for (int i = 0; i < 32; i += 8) {
    int k = k0 + ty + i, n = n0 + tx;
    if (k < K && n < N) t[ty + i][tx] = src[(long)k * N + n];
  }
  __syncthreads();
#pragma unroll
  for (int i = 0; i < 32; i += 8) {
    int n = n0 + ty + i, k = k0 + tx;
    if (k < K && n < N)
      dst[(long)n * K + k] = __float2bfloat16(t[tx][ty + i] * scale);
  }
}

// ---------------------------------------------------------------------------
// MEGA-PREP (unchanged from round 2)
// ---------------------------------------------------------------------------
__global__ __launch_bounds__(256) void prep_kernel(
    const float* __restrict__ ori, const float* __restrict__ W_val,
    const float* __restrict__ b_val, const float* __restrict__ tod_emb,
    const float* __restrict__ dow_emb, const float* __restrict__ node_emb,
    const float* __restrict__ W_in,
    const float* __restrict__ Wq, const float* __restrict__ Wk,
    const float* __restrict__ Wv, const float* __restrict__ Wo,
    const float* __restrict__ Wf1, const float* __restrict__ Wf2,
    const float* __restrict__ bq, const float* __restrict__ bk,
    const float* __restrict__ bv,
    const float* __restrict__ Wg1, const float* __restrict__ Wg2,
    const float* __restrict__ adj, const float* __restrict__ adj_sem,
    const float* __restrict__ b_in,
    const float* __restrict__ coeff2, const float* __restrict__ W_ce,
    const float* __restrict__ b_ce,
    __hip_bfloat16* __restrict__ xe, __hip_bfloat16* __restrict__ WinT,
    __hip_bfloat16* __restrict__ WqkvT, __hip_bfloat16* __restrict__ WoT,
    __hip_bfloat16* __restrict__ Wf1T, __hip_bfloat16* __restrict__ Wf2T,
    float* __restrict__ bqkv,
    __hip_bfloat16* __restrict__ WGPT,
    __hip_bfloat16* __restrict__ adjb, __hip_bfloat16* __restrict__ adjsb,
    float* __restrict__ Z, float* __restrict__ C2)
{
  __shared__ float t[32][33];
  int blk = blockIdx.x;

  if (blk < 9600) {                 // ---- embedding ----
    int idx = blk * 256 + threadIdx.x;
    int c = idx % EP;
    int r = idx / EP;               // bt*NP + node
    int node = r % NP;
    int bt = r / NP;
    float v = 0.f;
    if (node < NN && c < EMB) {
      long orr = (long)bt * NN + node;
      if (c < 24) {
        const float* x = ori + orr * 3;
        v = x[0] * W_val[c] + x[1] * W_val[24 + c] + x[2] * W_val[48 + c] + b_val[c];
      } else if (c < 48) {
        float f = ori[orr * 3 + 1];
        f = f - floorf(f);
        int tod = (int)(f * 288.f);
        tod = min(max(tod, 0), 287);
        v = tod_emb[tod * 24 + (c - 24)];
      } else if (c < 72) {
        float f = ori[orr * 3 + 2];
        f = f - floorf(f);
        int dow = (int)(f * 7.f);
        dow = min(max(dow, 0), 6);
        v = dow_emb[dow * 24 + (c - 48)];
      } else {
        v = node_emb[node * 80 + (c - 72)];
      }
    }
    xe[idx] = __float2bfloat16(v);
  } else if (blk < 9714) {          // ---- W_in transpose, s=10 cols only ----
    int q = blk - 9600;             // 57 x 2 tiles (cols 640..703)
    xpose_tile(W_in, WinT, 1824, 704, q % 57, 20 + q / 57, 1.f, t);
  } else if (blk < 9763) {          // ---- small-weight transposes + bias ----
    int b2 = blk - 9714;
    if (b2 == 48) {
      int th = threadIdx.x;
      if (th < 64) {
        bqkv[th] = bq[th] * 0.25f;  // score scale folded into q
        bqkv[64 + th] = bk[th];
        bqkv[128 + th] = bv[th];
      }
      return;
    }
    const float* src; __hip_bfloat16* dst;
    int K, N, bx, by; float scale = 1.f;
    if (b2 < 4)       { src = Wq;  dst = WqkvT;           K = 64;  N = 64;  bx = b2 & 1;        by = b2 >> 1;        scale = 0.25f; }
    else if (b2 < 8)  { src = Wk;  dst = WqkvT + 64 * 64; K = 64;  N = 64;  bx = (b2 - 4) & 1;  by = (b2 - 4) >> 1; }
    else if (b2 < 12) { src = Wv;  dst = WqkvT + 128 * 64;K = 64;  N = 64;  bx = (b2 - 8) & 1;  by = (b2 - 8) >> 1; }
    else if (b2 < 16) { src = Wo;  dst = WoT;             K = 64;  N = 64;  bx = (b2 - 12) & 1; by = (b2 - 12) >> 1; }
    else if (b2 < 32) { src = Wf1; dst = Wf1T;            K = 64;  N = 256; bx = (b2 - 16) % 2; by = (b2 - 16) / 2; }
    else              { src = Wf2; dst = Wf2T;            K = 256; N = 64;  bx = (b2 - 32) % 8; by = (b2 - 32) / 8; }
    xpose_tile(src, dst, K, N, bx, by, scale, t);
  } else {                          // ---- packs + Z init + C2 ----
    int b3 = blk - 9763;
    if (b3 < 80) {
      int idx = b3 * 256 + threadIdx.x;           // < 128*160
      int c = idx / EP, k = idx % EP;
      float v = 0.f;
      if (k < EMB) v = (c < 64) ? Wg1[k * 64 + c] : Wg2[k * 64 + (c - 64)];
      WGPT[idx] = __float2bfloat16(v);
    } else if (b3 < 480) {
      int idx = (b3 - 80) * 256 + threadIdx.x;    // < 320*320
      int m = idx / NP, k = idx % NP;
      float v1 = 0.f, v2 = 0.f;
      if (m < NN && k < NN) { v1 = adj[m * NN + k]; v2 = adj_sem[m * NN + k]; }
      adjb[idx] = __float2bfloat16(v1);
      adjsb[idx] = __float2bfloat16(v2);
    } else if (b3 < 787) {
      int idx = (b3 - 480) * 256 + threadIdx.x;   // < 1228*64
      Z[idx] = b_in[640 + (idx & 63)];
    } else {
      int idx = (b3 - 787) * 256 + threadIdx.x;   // < 13508*64
      int row = idx >> 6, h = idx & 63;           // row = (b*N+n)*S + s
      float a0 = coeff2[(long)row * 2];
      float a1 = coeff2[(long)row * 2 + 1];
      C2[idx] = a0 * W_ce[h] + a1 * W_ce[64 + h] + b_ce[h];
    }
  }
}

// ---------------------------------------------------------------------------
// xg_mfma (unchanged)
// ---------------------------------------------------------------------------
__global__ __launch_bounds__(256) void xg_mfma(
    const __hip_bfloat16* __restrict__ XE, const __hip_bfloat16* __restrict__ WGPT,
    __hip_bfloat16* __restrict__ XGT)
{
  int bt = blockIdx.x;
  int tid = threadIdx.x, w = tid >> 6, l = tid & 63;
  int m0 = blockIdx.y * 64 + w * 16;      // node tile
  int cq = l & 15, rq = l >> 4;

  short8 af[5];
  const short* Ap = (const short*)XE + ((long)bt * NP + m0 + cq) * EP + rq * 8;
#pragma unroll
  for (int kk = 0; kk < 5; ++kk) af[kk] = *(const short8*)(Ap + kk * 32);

#pragma unroll
  for (int ct = 0; ct < 8; ++ct) {
    const short* Bp = (const short*)WGPT + (long)(ct * 16 + cq) * EP + rq * 8;
    floatx4 acc = {0.f, 0.f, 0.f, 0.f};
#pragma unroll
    for (int kk = 0; kk < 5; ++kk)
      acc = MFMA_B16(af[kk], *(const short8*)(Bp + kk * 32), acc);
    short4a pk;
#pragma unroll
    for (int r = 0; r < 4; ++r) pk[r] = f2bf(acc[r]);
    *(short4a*)((short*)XGT + ((long)bt * 128 + ct * 16 + cq) * NP + m0 + rq * 4) = pk;
  }
}

// ---------------------------------------------------------------------------
// gcn_mfma (unchanged)
// ---------------------------------------------------------------------------
__global__ __launch_bounds__(256) void gcn_mfma(
    const __hip_bfloat16* __restrict__ XGT, const __hip_bfloat16* __restrict__ adjb,
    const __hip_bfloat16* __restrict__ adjsb, const float* __restrict__ bg,
    float* __restrict__ GT)
{
  int bt = blockIdx.x;
  int tid = threadIdx.x, w = tid >> 6, l = tid & 63;
  int n0 = blockIdx.y * 64;
  int cq = l & 15, rq = l >> 4;

  short8 a1[10], a2[10];
  const short* A1p = (const short*)XGT + ((long)bt * 128 + w * 16 + cq) * NP + rq * 8;
  const short* A2p = A1p + 64 * NP;
#pragma unroll
  for (int kk = 0; kk < 10; ++kk) {
    a1[kk] = *(const short8*)(A1p + kk * 32);
    a2[kk] = *(const short8*)(A2p + kk * 32);
  }

  float bgv[4];
#pragma unroll
  for (int r = 0; r < 4; ++r) bgv[r] = bg[w * 16 + rq * 4 + r];

#pragma unroll
  for (int nt = 0; nt < 4; ++nt) {
    const short* B1p = (const short*)adjb + (long)(n0 + nt * 16 + cq) * NP + rq * 8;
    const short* B2p = (const short*)adjsb + (long)(n0 + nt * 16 + cq) * NP + rq * 8;
    floatx4 acc = {0.f, 0.f, 0.f, 0.f};
#pragma unroll
    for (int kk = 0; kk < 10; ++kk) {
      acc = MFMA_B16(a1[kk], *(const short8*)(B1p + kk * 32), acc);
      acc = MFMA_B16(a2[kk], *(const short8*)(B2p + kk * 32), acc);
    }
    int node = n0 + nt * 16 + cq;
    if (node < NN) {
      float4 pk;
      pk.x = fmaxf(acc[0] + bgv[0], 0.f);
      pk.y = fmaxf(acc[1] + bgv[1], 0.f);
      pk.z = fmaxf(acc[2] + bgv[2], 0.f);
      pk.w = fmaxf(acc[3] + bgv[3], 0.f);
      *(float4*)(GT + (((long)bt * NP + node) * 64 + w * 16 + rq * 4)) = pk;
    }
  }
}

// ---------------------------------------------------------------------------
// x_in GEMM — s=10 output block only.  grid (20, 4).
// ---------------------------------------------------------------------------
__global__ __launch_bounds__(256) void gemm_xin(
    const __hip_bfloat16* __restrict__ XE, const __hip_bfloat16* __restrict__ BT,
    float* __restrict__ C)
{
  int tid = threadIdx.x, w = tid >> 6, l = tid & 63;
  int m0 = blockIdx.x * 64 + w * 16;
  const int n0 = 640;                 // s=10 column block of W_in
  int k0s = blockIdx.y * 480;
  int k0e = min(1824, k0s + 480);

  int cq = l & 15, rq = l >> 4;
  int arow = min(m0 + cq, 1227);
  int ab = arow / NN, an = arow - ab * NN;
  const short* Abase = (const short*)XE;
  const short* Bp = (const short*)BT + rq * 8;

  floatx4 acc[4] = {};
  for (int k0 = k0s; k0 < k0e; k0 += 32) {
    int kk = k0 + rq * 8;
    int t = kk / EMB;
    int c = kk - t * EMB;
    short8 a = *(const short8*)(Abase + (((long)(ab * TT + t)) * NP + an) * EP + c);
#pragma unroll
    for (int nt = 0; nt < 4; ++nt) {
      short8 b = *(const short8*)(Bp + (long)(n0 + nt * 16 + cq) * 1824 + k0);
      acc[nt] = MFMA_B16(a, b, acc[nt]);
    }
  }
#pragma unroll
  for (int nt = 0; nt < 4; ++nt) {
    int c = nt * 16 + cq;
#pragma unroll
    for (int r = 0; r < 4; ++r) {
      int row = m0 + rq * 4 + r;
      if (row < 1228) atomicAdd(&C[(long)row * 64 + c], acc[nt][r]);
    }
  }
}

// ---------------------------------------------------------------------------
// HeteroGCN head (unchanged)
// ---------------------------------------------------------------------------
__global__ __launch_bounds__(256) void gcn_out(
    const float* __restrict__ GT, const float* __restrict__ Wgo,
    const float* __restrict__ bgo, const float* __restrict__ w_het,
    float* __restrict__ out)
{
  __shared__ float buf[4][TT * 64];
  int wave = threadIdx.x >> 6, lane = threadIdx.x & 63;
  int bn = blockIdx.x * 4 + wave;        // 307*4 = 1228 exact
  int b = bn / NN, n = bn % NN;
  float* bw = buf[wave];
  for (int idx = lane; idx < TT * 64; idx += 64) {
    int t = idx >> 6, h = idx & 63;
    bw[idx] = GT[(((long)(b * TT + t)) * NP + n) * 64 + h];
  }
  float acc[12] = {};
#pragma unroll
  for (int j = 0; j < 12; ++j) {
    int k = j * 64 + lane;
    float g = bw[k];
    const float* wr = Wgo + (long)k * 12;
#pragma unroll
    for (int o = 0; o < 12; ++o) acc[o] += g * wr[o];
  }
#pragma unroll
  for (int o = 0; o < 12; ++o) acc[o] = wave_sum(acc[o]);
  if (lane == 0) {
    float wh = w_het[0];
#pragma unroll
    for (int o = 0; o < 12; ++o)
      out[((long)b * 12 + o) * NN + n] = wh * (acc[o] + bgo[o]);
  }
}

// ---------------------------------------------------------------------------
// initial QKV from Z (1228 x 64 fp32).  grid 20 = 4b x 5 mt, 256 threads.
// Proven gp_qkv body with the new Z layout.
// ---------------------------------------------------------------------------
__global__ __launch_bounds__(256) void qkv_init(
    const float* __restrict__ Z, const __hip_bfloat16* __restrict__ WT,
    const float* __restrict__ bqkv,
    short* __restrict__ Qb, short* __restrict__ Kb, short* __restrict__ Vtb)
{
  int q = blockIdx.x;
  int b = q / 5, mt = q % 5;
  int tid = threadIdx.x, w = tid >> 6, l = tid & 63;
  int m0 = mt * 64 + w * 16;
  int cq = l & 15, rq = l >> 4;

  int node0 = m0 + cq;
  int nc = min(node0, NN - 1);
  const float* zp = Z + ((long)(b * NN + nc)) * 64 + rq * 8;
  short8 a0, a1;
#pragma unroll
  for (int j = 0; j < 8; ++j) { a0[j] = f2bf(zp[j]); a1[j] = f2bf(zp[32 + j]); }

#pragma unroll
  for (int nt = 0; nt < 12; ++nt) {
    const short* Bp = (const short*)WT + (long)(nt * 16 + cq) * 64 + rq * 8;
    floatx4 acc = {0.f, 0.f, 0.f, 0.f};
    acc = MFMA_B16(a0, *(const short8*)Bp, acc);
    acc = MFMA_B16(a1, *(const short8*)(Bp + 32), acc);
    int c = nt * 16 + cq;
    float bias = bqkv[c];
#pragma unroll
    for (int r = 0; r < 4; ++r) {
      int node = m0 + rq * 4 + r;
      if (node < NN) {
        short v = f2bf(acc[r] + bias);
        if (c < 64)       Qb[((long)b * NP + node) * 64 + c] = v;
        else if (c < 128) Kb[((long)b * NP + node) * 64 + (c - 64)] = v;
        else              Vtb[((long)b * 64 + (c - 128)) * NP + node] = v;
      }
    }
  }
}

// ---------------------------------------------------------------------------
// LN stats helper: mean/var over 64 cols split as 16 lanes x 4 waves.
// ---------------------------------------------------------------------------
__device__ __forceinline__ void ln_stats4(
    const float* x, float (*R0)[16], float (*R1)[16],
    int w, int cq, int rq, float* mean, float* rstd)
{
  float p[4];
#pragma unroll
  for (int r = 0; r < 4; ++r) {
    float s = x[r];
#pragma unroll
    for (int o2 = 1; o2 <= 8; o2 <<= 1) s += __shfl_xor(s, o2);
    p[r] = s;
  }
  if (cq == 0) {
#pragma unroll
    for (int r = 0; r < 4; ++r) R0[w][rq * 4 + r] = p[r];
  }
  __syncthreads();
#pragma unroll
  for (int r = 0; r < 4; ++r) {
    int rr = rq * 4 + r;
    mean[r] = (R0[0][rr] + R0[1][rr] + R0[2][rr] + R0[3][rr]) * (1.f / 64.f);
  }
#pragma unroll
  for (int r = 0; r < 4; ++r) {
    float d = x[r] - mean[r];
    float s = d * d;
#pragma unroll
    for (int o2 = 1; o2 <= 8; o2 <<= 1) s += __shfl_xor(s, o2);
    p[r] = s;
  }
  if (cq == 0) {
#pragma unroll
    for (int r = 0; r < 4; ++r) R1[w][rq * 4 + r] = p[r];
  }
  __syncthreads();
#pragma unroll
  for (int r = 0; r < 4; ++r) {
    int rr = rq * 4 + r;
    float vs = R1[0][rr] + R1[1][rr] + R1[2][rr] + R1[3][rr];
    rstd[r] = rsqrtf(vs * (1.f / 64.f) + 1e-5f);
  }
}

// ---------------------------------------------------------------------------
// scan_step: ONE dispatch per Euler iteration.  Grid (20 tiles, 4 batches),
// 256 threads.  Each block owns 16 output rows of batch b:
//   stage K/V^T(b) -> LDS;  attn (wave = head, proven body, O -> LDS);
//   fused step (proven block_step3 body, A from LDS);  QKV(next) -> global
//   (or final LN + W_end on the last iteration).
// ---------------------------------------------------------------------------
__global__ __launch_bounds__(256) void scan_step(
    const short* __restrict__ Qb, const short* __restrict__ Kb,
    const short* __restrict__ Vtb,
    short* __restrict__ Qn, short* __restrict__ Kn, short* __restrict__ Vtn,
    float* __restrict__ Z, const float* __restrict__ C2,
    const float* __restrict__ W_tp2, const float* __restrict__ b_tp2,
    const __hip_bfloat16* __restrict__ WqkvT, const float* __restrict__ bqkv,
    const __hip_bfloat16* __restrict__ WoT, const float* __restrict__ bo,
    const float* __restrict__ ln1g, const float* __restrict__ ln1b,
    const __hip_bfloat16* __restrict__ Wf1T, const float* __restrict__ bf1,
    const __hip_bfloat16* __restrict__ Wf2T, const float* __restrict__ bf2,
    const float* __restrict__ ln2g, const float* __restrict__ ln2b,
    const float* __restrict__ lnfg, const float* __restrict__ lnfb,
    const float* __restrict__ W_end, const float* __restrict__ b_end,
    const float* __restrict__ w_acl, float* __restrict__ out, int iter)
{
  __shared__ __align__(16) short KL[NP * KP];    // 46080 B
  __shared__ __align__(16) short VT[64 * VP];    // 41984 B
  __shared__ __align__(16) short Pd[4][1280];    // 10240 B
  __shared__ __align__(16) short Ot[16 * OTP];   //  2304 B
  __shared__ __align__(16) short Hl[16 * HLP];   //  2304 B
  __shared__ __align__(16) short Hc[16 * HCP];   //  8448 B
  __shared__ float Red[2][4][16];                //   512 B

  const short8 z8 = {0, 0, 0, 0, 0, 0, 0, 0};
  const floatx4 zf4 = {0.f, 0.f, 0.f, 0.f};

  int b = blockIdx.y;
  int tile = blockIdx.x;
  int m0 = tile * 16;
  int tid = threadIdx.x;
  int w = tid >> 6, l = tid & 63;
  int cq = l & 15, rq = l >> 4;

  // ---- stage K (zero rows >= NN) ----
  for (int ch = tid; ch < NP * 8; ch += 256) {
    int node = ch >> 3, part = (ch & 7) * 8;
    short8 kv = z8;
    if (node < NN) kv = *(const short8*)(Kb + ((long)b * NP + node) * 64 + part);
    *(short8*)&KL[node * KP + part] = kv;
  }
  // ---- stage V^T (zero cols >= NN) ----
  for (int ch = tid; ch < 64 * 40; ch += 256) {
    int d = ch / 40, k8 = (ch % 40) * 8;
    short8 vv = z8;
    if (k8 + 7 < NN) {
      vv = *(const short8*)(Vtb + ((long)b * 64 + d) * NP + k8);
    } else {
#pragma unroll
      for (int j = 0; j < 8; ++j)
        if (k8 + j < NN) vv[j] = Vtb[((long)b * 64 + d) * NP + k8 + j];
    }
    *(short8*)&VT[d * VP + k8] = vv;
  }
  __syncthreads();

  // ================= attention (wave = head, 16 queries = this tile) ======
  {
    int head = w;
    int m = cq, quad = rq;
    int qv = m0 + m;
    short8 qf = z8;
    if (quad < 2 && qv < NN)
      qf = *(const short8*)(Qb + ((long)b * NP + qv) * 64 + head * 16 + quad * 8);

    short* Pw0 = &Pd[w][0];
    short* Pw1 = &Pd[w][640];
    float sum = 0.f;
    floatx4 oa = zf4, ob = zf4;
    const short* Vb = &VT[(head * 16 + m) * VP];
    for (int c = 0; c < 10; ++c) {
      short8 kf0 = z8, kf1 = z8;
      if (quad < 2) {
        kf0 = *(const short8*)&KL[((2 * c) * 16 + m) * KP + head * 16 + quad * 8];
        kf1 = *(const short8*)&KL[((2 * c + 1) * 16 + m) * KP + head * 16 + quad * 8];
      }
      floatx4 s0 = MFMA_B16(kf0, qf, zf4);
      floatx4 s1 = MFMA_B16(kf1, qf, zf4);
      float e0[4], e1[4];
#pragma unroll
      for (int j = 0; j < 4; ++j) {
        e0[j] = __expf(fminf(s0[j], 30.f));
        e1[j] = __expf(fminf(s1[j], 30.f));
      }
      if (c == 9) {                  // keys >= 307 masked out
        if (quad == 0) e1[3] = 0.f;
        else { e1[0] = 0.f; e1[1] = 0.f; e1[2] = 0.f; e1[3] = 0.f; }
      }
      sum += e0[0] + e0[1] + e0[2] + e0[3] + e1[0] + e1[1] + e1[2] + e1[3];
      short4a p0, p1;
#pragma unroll
      for (int j = 0; j < 4; ++j) { p0[j] = f2bf(e0[j]); p1[j] = f2bf(e1[j]); }
      short* Pw = (c & 1) ? Pw1 : Pw0;
      *(short4a*)&Pw[m * PLP + quad * 4] = p0;
      *(short4a*)&Pw[m * PLP + 16 + quad * 4] = p1;
      short8 pf = *(const short8*)&Pw[m * PLP + quad * 8];
      short8 vf = *(const short8*)(Vb + c * 32 + quad * 8);
      if (c & 1) ob = MFMA_B16(vf, pf, ob);
      else       oa = MFMA_B16(vf, pf, oa);
    }
    sum += __shfl_xor(sum, 16);
    sum += __shfl_xor(sum, 32);
    float inv = 1.f / sum;
    short4a pk;
#pragma unroll
    for (int r = 0; r < 4; ++r) pk[r] = f2bf((oa[r] + ob[r]) * inv);
    *(short4a*)&Ot[m * OTP + head * 16 + quad * 4] = pk;  // O -> LDS
  }
  __syncthreads();   // O tile complete; KL/VT dead below

  // ================= fused step (proven block_step3 body) =================
  int col = w * 16 + cq;
  float g1 = ln1g[col], b1 = ln1b[col];
  float g2 = ln2g[col], b2v = ln2b[col];
  float f2 = bf2[col];
  float bov = bo[col];

  // ---- Wo GEMM + residual ----
  short8 a0 = *(const short8*)&Ot[cq * OTP + rq * 8];
  short8 a1 = *(const short8*)&Ot[cq * OTP + 32 + rq * 8];
  const short* Bwo = (const short*)WoT + (long)col * 64 + rq * 8;
  floatx4 acc0 = zf4;
  acc0 = MFMA_B16(a0, *(const short8*)Bwo, acc0);
  acc0 = MFMA_B16(a1, *(const short8*)(Bwo + 32), acc0);

  float x[4];
  bool val[4]; int zov[4], bnv[4];
#pragma unroll
  for (int r = 0; r < 4; ++r) {
    int nodev = m0 + rq * 4 + r;
    val[r] = nodev < NN;
    int nc = min(nodev, NN - 1);
    bnv[r] = b * NN + nc;
    zov[r] = bnv[r] * 64;
    x[r] = acc0[r] + bov + Z[zov[r] + col];
  }

  // ---- LN1 ----
  float mean[4], rstd[4];
  ln_stats4(x, Red[0], Red[1], w, cq, rq, mean, rstd);
  float h1r[4];
#pragma unroll
  for (int r = 0; r < 4; ++r) {
    float h = (x[r] - mean[r]) * rstd[r] * g1 + b1;
    h1r[r] = h;
    Hl[(rq * 4 + r) * HLP + col] = f2bf(h);
  }
  __syncthreads();   // h1 complete

  // ---- FFN A ----
  short8 ha0 = *(const short8*)&Hl[cq * HLP + rq * 8];
  short8 ha1 = *(const short8*)&Hl[cq * HLP + 32 + rq * 8];
#pragma unroll
  for (int jj = 0; jj < 4; ++jj) {
    int ht = w * 4 + jj;
    const short* Bq = (const short*)Wf1T + (long)(ht * 16 + cq) * 64 + rq * 8;
    floatx4 ac = zf4;
    ac = MFMA_B16(ha0, *(const short8*)Bq, ac);
    ac = MFMA_B16(ha1, *(const short8*)(Bq + 32), ac);
    float bv = bf1[ht * 16 + cq];
#pragma unroll
    for (int r = 0; r < 4; ++r)
      Hc[(rq * 4 + r) * HCP + ht * 16 + cq] = f2bf(fmaxf(ac[r] + bv, 0.f));
  }
  __syncthreads();   // hidden complete

  // ---- FFN B ----
  {
    const short* Bq = (const short*)Wf2T + (long)col * 256 + rq * 8;
    floatx4 ac = zf4;
#pragma unroll
    for (int kk = 0; kk < 8; ++kk) {
      short8 pf = *(const short8*)&Hc[cq * HCP + kk * 32 + rq * 8];
      ac = MFMA_B16(pf, *(const short8*)(Bq + kk * 32), ac);
    }
#pragma unroll
    for (int r = 0; r < 4; ++r) x[r] = h1r[r] + ac[r] + f2;
  }
  __syncthreads();   // Hc reads done (Fin may reuse)

  // ---- LN2 ----
  ln_stats4(x, Red[0], Red[1], w, cq, rq, mean, rstd);

  // ---- tanh + Euler update ----
  float wt[SS];
#pragma unroll
  for (int s2 = 0; s2 < SS; ++s2) wt[s2] = W_tp2[s2 * (SS * SS) + 110 + iter];
  float btp = b_tp2[110 + iter];
#pragma unroll
  for (int r = 0; r < 4; ++r) {
    float t = tanhf((x[r] - mean[r]) * rstd[r] * g2 + b2v);
    float accw = btp;
#pragma unroll
    for (int s2 = 0; s2 < SS; ++s2)
      accw += C2[((long)bnv[r] * SS + s2) * 64 + col] * wt[s2];
    if (val[r]) {
      float zn = Z[zov[r] + col] + t * accw;
      Z[zov[r] + col] = zn;
      Hl[(rq * 4 + r) * HLP + col] = f2bf(zn);
      x[r] = zn;
    }
  }
  __syncthreads();   // zn chunk complete

  if (iter < SS - 1) {
    // ---- QKV for next iter -> global ----
    short8 zb0 = *(const short8*)&Hl[cq * HLP + rq * 8];
    short8 zb1 = *(const short8*)&Hl[cq * HLP + 32 + rq * 8];
#pragma unroll
    for (int jj = 0; jj < 3; ++jj) {
      int nt = w * 3 + jj;
      const short* Bq = (const short*)WqkvT + (long)(nt * 16 + cq) * 64 + rq * 8;
      floatx4 ac = zf4;
      ac = MFMA_B16(zb0, *(const short8*)Bq, ac);
      ac = MFMA_B16(zb1, *(const short8*)(Bq + 32), ac);
      int c = nt * 16 + cq;
      float bias = bqkv[c];
#pragma unroll
      for (int r = 0; r < 4; ++r) {
        int nd = m0 + rq * 4 + r;
        if (nd < NN) {
          short v = f2bf(ac[r] + bias);
          if (c < 64)       Qn[((long)b * NP + nd) * 64 + c] = v;
          else if (c < 128) Kn[((long)b * NP + nd) * 64 + (c - 64)] = v;
          else              Vtn[((long)b * 64 + (c - 128)) * NP + nd] = v;
        }
      }
    }
  } else {
    // ---- final: zT = LN(zn; lnf); out += w_acl*(zT@W_end + b_end) ----
    ln_stats4(x, Red[0], Red[1], w, cq, rq, mean, rstd);
    float gf = lnfg[col], bff = lnfb[col];
    float zT[4];
#pragma unroll
    for (int r = 0; r < 4; ++r)
      zT[r] = (x[r] - mean[r]) * rstd[r] * gf + bff;
    float* Fin = (float*)Hc;   // free after FFN-B barrier
#pragma unroll
    for (int o = 0; o < 12; ++o) {
      float pr[4];
#pragma unroll
      for (int r = 0; r < 4; ++r) {
        float p = zT[r] * W_end[col * 12 + o];
#pragma unroll
        for (int o2 = 1; o2 <= 8; o2 <<= 1) p += __shfl_xor(p, o2);
        pr[r] = p;
      }
      if (cq == 0) {
#pragma unroll
        for (int r = 0; r < 4; ++r) Fin[(o * 4 + w) * 16 + rq * 4 + r] = pr[r];
      }
    }
    __syncthreads();
    if (w == 0 && l < 16) {
      int nd = m0 + l;
      if (nd < NN) {
        float wa = w_acl[0];
#pragma unroll
        for (int o = 0; o < 12; ++o) {
          float p = Fin[(o * 4 + 0) * 16 + l] + Fin[(o * 4 + 1) * 16 + l] +
                    Fin[(o * 4 + 2) * 16 + l] + Fin[(o * 4 + 3) * 16 + l];
          int oi = (b * 12 + o) * NN + nd;
          out[oi] = out[oi] + wa * (p + b_end[o]);
        }
      }
    }
  }
}

// ---------------------------------------------------------------------------
extern "C" void kernel_launch(void* const* d_in, const int* in_sizes, int n_in,
                              void* d_out, int out_size, void* d_ws, size_t ws_size,
                              hipStream_t stream)
{
  (void)in_sizes; (void)n_in; (void)out_size; (void)ws_size;

  const float* ori_x    = (const float*)d_in[0];
  const float* coeff2   = (const float*)d_in[2];
  const float* W_val    = (const float*)d_in[5];
  const float* b_val    = (const float*)d_in[6];
  const float* tod_emb  = (const float*)d_in[7];
  const float* dow_emb  = (const float*)d_in[8];
  const float* node_emb = (const float*)d_in[9];
  const float* W_in     = (const float*)d_in[10];
  const float* b_in     = (const float*)d_in[11];
  const float* W_ce     = (const float*)d_in[12];
  const float* b_ce     = (const float*)d_in[13];
  const float* W_tp2    = (const float*)d_in[14];
  const float* b_tp2    = (const float*)d_in[15];
  const float* Wq = (const float*)d_in[20];
  const float* Wk = (const float*)d_in[21];
  const float* Wv = (const float*)d_in[22];
  const float* Wo = (const float*)d_in[23];
  const float* bq = (const float*)d_in[24];
  const float* bk = (const float*)d_in[25];
  const float* bv = (const float*)d_in[26];
  const float* bo = (const float*)d_in[27];
  const float* ln1_g = (const float*)d_in[28];
  const float* ln1_b = (const float*)d_in[29];
  const float* Wf1   = (const float*)d_in[30];
  const float* bf1   = (const float*)d_in[31];
  const float* Wf2   = (const float*)d_in[32];
  const float* bf2   = (const float*)d_in[33];
  const float* ln2_g = (const float*)d_in[34];
  const float* ln2_b = (const float*)d_in[35];
  const float* lnf_g = (const float*)d_in[36];
  const float* lnf_b = (const float*)d_in[37];
  const float* W_end = (const float*)d_in[38];
  const float* b_end = (const float*)d_in[39];
  const float* w_acl = (const float*)d_in[40];
  const float* w_het = (const float*)d_in[41];
  const float* adj     = (const float*)d_in[42];
  const float* adj_sem = (const float*)d_in[43];
  const float* Wg1 = (const float*)d_in[44];
  const float* Wg2 = (const float*)d_in[45];
  const float* bg  = (const float*)d_in[46];
  const float* Wgo = (const float*)d_in[47];
  const float* bgo = (const float*)d_in[48];
  float* out = (float*)d_out;
  float* ws  = (float*)d_ws;

  // ---- workspace layout (float offsets, 16-float aligned) ----
  float* Z  = ws;                                            // 1228*64 = 78592
  float* C2 = ws + 78592;                                    // 13508*64 = 864512
  __hip_bfloat16* WinT  = (__hip_bfloat16*)(ws + 943104);    // 704*1824 bf16
  __hip_bfloat16* WqkvT = (__hip_bfloat16*)(ws + 1585152);   // 192*64
  __hip_bfloat16* WoT   = (__hip_bfloat16*)(ws + 1591296);   // 64*64
  __hip_bfloat16* Wf1T  = (__hip_bfloat16*)(ws + 1593344);   // 256*64
  __hip_bfloat16* Wf2T  = (__hip_bfloat16*)(ws + 1601536);   // 64*256
  float* BQKV = ws + 1609728;                                // 192 (+pad)
  short* QA = (short*)(ws + 1609984);                        // 4*320*64 bf16 each
  short* KA = (short*)(ws + 1650944);
  short* VA = (short*)(ws + 1691904);
  short* QB = (short*)(ws + 1732864);
  short* KB = (short*)(ws + 1773824);
  short* VB = (short*)(ws + 1814784);
  float* POOL = ws + 1855744;
  __hip_bfloat16* XEMBb = (__hip_bfloat16*)POOL;             // 48*320*160
  __hip_bfloat16* XGT   = (__hip_bfloat16*)(POOL + 1228800); // 48*128*320
  float* GT             = POOL + 2211840;                    // 48*320*64 fp32
  __hip_bfloat16* ADJB  = (__hip_bfloat16*)(POOL + 3194880); // 320*320
  __hip_bfloat16* ADJSB = (__hip_bfloat16*)(POOL + 3246080); // 320*320
  __hip_bfloat16* WGPT  = (__hip_bfloat16*)(POOL + 3297280); // 128*160

  // ---- phase 1 ----
  prep_kernel<<<dim3(13927), dim3(256), 0, stream>>>(
      ori_x, W_val, b_val, tod_emb, dow_emb, node_emb, W_in,
      Wq, Wk, Wv, Wo, Wf1, Wf2, bq, bk, bv,
      Wg1, Wg2, adj, adj_sem, b_in, coeff2, W_ce, b_ce,
      XEMBb, WinT, WqkvT, WoT, Wf1T, Wf2T, BQKV,
      WGPT, ADJB, ADJSB, Z, C2);
  gemm_xin<<<dim3(20, 4), dim3(256), 0, stream>>>(XEMBb, WinT, Z);
  xg_mfma<<<dim3(NBT, 5), dim3(256), 0, stream>>>(XEMBb, WGPT, XGT);
  gcn_mfma<<<dim3(NBT, 5), dim3(256), 0, stream>>>(XGT, ADJB, ADJSB, bg, GT);
  gcn_out<<<dim3(307), dim3(256), 0, stream>>>(GT, Wgo, bgo, w_het, out);
  qkv_init<<<dim3(20), dim3(256), 0, stream>>>(Z, WqkvT, BQKV, QA, KA, VA);

  // ---- phase 2: 11 fused scan steps (attn + step + next-QKV per dispatch) --
  for (int i = 0; i < SS; ++i) {
    short *Qr, *Kr, *Vr, *Qw, *Kw, *Vw;
    if (i & 1) { Qr = QB; Kr = KB; Vr = VB; Qw = QA; Kw = KA; Vw = VA; }
    else       { Qr = QA; Kr = KA; Vr = VA; Qw = QB; Kw = KB; Vw = VB; }
    scan_step<<<dim3(20, 4), dim3(256), 0, stream>>>(
        Qr, Kr, Vr, Qw, Kw, Vw,
        Z, C2, W_tp2, b_tp2, WqkvT, BQKV, WoT, bo, ln1_g, ln1_b,
        Wf1T, bf1, Wf2T, bf2, ln2_g, ln2_b, lnf_g, lnf_b,
        W_end, b_end, w_acl, out, i);
  }
}